// Round 4
// baseline (360.453 us; speedup 1.0000x reference)
//
#include <hip/hip_runtime.h>
#include <hip/hip_bf16.h>

#define C_ 384
#define B_ 16
#define H_ 56
#define W_ 56
#define PAD_ 6
#define LW_ 68              // 56 + 2*6
#define PLANE_ (LW_ * LW_)  // 4624 floats
#define NPL_ 4              // planes (same channel, different batch) per block
#define TPB_ 448            // 7 waves; 112 threads per plane (14 xg * 8 yg)

// Fold all 7 branches (conv + BN) into one 13x13 kernel per channel + bias.
// weff layout: [C][13][16] (rows padded to 16 floats for aligned scalar loads)
__global__ void build_weights_kernel(
    const float* __restrict__ lk, const float* __restrict__ obn,
    const float* __restrict__ w5, const float* __restrict__ w7a,
    const float* __restrict__ w7b, const float* __restrict__ w3a,
    const float* __restrict__ w3b, const float* __restrict__ w3c,
    const float* __restrict__ brbn,
    float* __restrict__ weff, float* __restrict__ bias)
{
    int c = blockIdx.x;
    int t = threadIdx.x;

    float sc[7], sh[7];
    {
        float g = obn[c], b = obn[C_ + c], m = obn[2 * C_ + c], v = obn[3 * C_ + c];
        float s = g * rsqrtf(v + 1e-5f);
        sc[0] = s; sh[0] = b - m * s;
    }
#pragma unroll
    for (int i = 0; i < 6; ++i) {
        float g = brbn[(i * 4 + 0) * C_ + c], b = brbn[(i * 4 + 1) * C_ + c];
        float m = brbn[(i * 4 + 2) * C_ + c], v = brbn[(i * 4 + 3) * C_ + c];
        float s = g * rsqrtf(v + 1e-5f);
        sc[i + 1] = s; sh[i + 1] = b - m * s;
    }

    if (t < 13 * 16) {
        int py = t >> 4, px = t & 15;
        float a = 0.f;
        if (px < 13) {
            int dy = py - 6, dx = px - 6;
            a = sc[0] * lk[c * 169 + py * 13 + px];   // 13x13, dil 1
#define ADDBR(Wp, K, R, SI)                                               \
            {                                                             \
                const int half = ((K) - 1) / 2;                           \
                if (dy % (R) == 0 && dx % (R) == 0) {                     \
                    int iy = dy / (R), ix = dx / (R);                     \
                    if (iy >= -half && iy <= half && ix >= -half && ix <= half) \
                        a += sc[SI] * Wp[c * (K) * (K) + (iy + half) * (K) + (ix + half)]; \
                }                                                         \
            }
            ADDBR(w5,  5, 1, 1)
            ADDBR(w7a, 7, 1, 2)
            ADDBR(w7b, 7, 2, 3)
            ADDBR(w3a, 3, 3, 4)
            ADDBR(w3b, 3, 4, 5)
            ADDBR(w3c, 3, 5, 6)
#undef ADDBR
        }
        weff[c * 208 + t] = a;
    }
    if (t == 0) {
        float s = 0.f;
#pragma unroll
        for (int i = 0; i < 7; ++i) s += sh[i];
        bias[c] = s;
    }
}

// One block: 4 planes (batches bg*4..bg*4+3) of channel c.
// Per plane: 112 threads, each computes a 4-wide x 7-tall output tile.
// ky-outer, weight-stationary: rolling 7-row register window, one new input
// row (4x ds_read_b128) + one weight row (s_load_dwordx16) per step, then a
// 364-FMA burst. sched_barrier(0) pins the loads ahead of each burst so the
// compiler can't collapse the window's liveness (R2 failure mode).
__global__ __launch_bounds__(TPB_) void dwconv13_kernel(
    const float* __restrict__ x, const float* __restrict__ weff,
    const float* __restrict__ bias, float* __restrict__ out)
{
    __shared__ float sx[NPL_ * PLANE_];   // 73984 B

    int bid = blockIdx.x;
    int c  = bid % C_;
    int bg = bid / C_;   // 0..3
    int t  = threadIdx.x;

    // ---- Issue global loads FIRST so their latency hides under zeroing. ----
    // 4 planes * 56 rows * 14 float4-groups = 3136 slots = 7 per thread exactly.
    float4 vv[7];
    int    dd[7];
#pragma unroll
    for (int k = 0; k < 7; ++k) {
        int slot = t + k * TPB_;
        int p    = slot / 784;            // 784 = 56*14
        int rem  = slot - p * 784;
        int iy   = rem / 14;
        int g    = rem - iy * 14;
        const float* xp = x + ((size_t)(bg * NPL_ + p) * C_ + c) * (H_ * W_);
        vv[k] = *(const float4*)(xp + iy * W_ + g * 4);
        dd[k] = p * PLANE_ + (iy + PAD_) * LW_ + PAD_ + g * 4;   // even
    }

    // ---- Zero the whole LDS region (halo = conv padding) meanwhile. ----
    {
        float4 z = make_float4(0.f, 0.f, 0.f, 0.f);
        float4* s4 = (float4*)sx;
#pragma unroll
        for (int k = 0; k < 11; ++k) {
            int slot = t + k * TPB_;
            if (k < 10 || slot < (NPL_ * PLANE_) / 4) s4[slot] = z;
        }
    }
    __syncthreads();

    // ---- Commit staged rows (vmcnt waits happen here, mostly drained). ----
#pragma unroll
    for (int k = 0; k < 7; ++k) {
        float2* wp = (float2*)(sx + dd[k]);
        wp[0] = make_float2(vv[k].x, vv[k].y);
        wp[1] = make_float2(vv[k].z, vv[k].w);
    }
    __syncthreads();

    const float* wc = weff + c * 208;   // block-uniform -> s_load path
    float bv = bias[c];

    int p   = t / 112;
    int rem = t - p * 112;
    int xg  = rem % 14;       // x0 = 4*xg  (16B aligned in LDS and in out)
    int yg  = rem / 14;       // y0 = 7*yg
    int x0 = xg * 4, y0 = yg * 7;
    const float* sp = sx + p * PLANE_;

    float acc[7][4];
#pragma unroll
    for (int i = 0; i < 7; ++i)
#pragma unroll
        for (int j = 0; j < 4; ++j) acc[i][j] = bv;

#define LOADROW(buf, r) {                                                  \
        const float4* rp = (const float4*)(sp + (y0 + (r)) * LW_ + x0);    \
        *(float4*)((buf) + 0)  = rp[0];                                    \
        *(float4*)((buf) + 4)  = rp[1];                                    \
        *(float4*)((buf) + 8)  = rp[2];                                    \
        *(float4*)((buf) + 12) = rp[3];                                    \
    }

    // acc[tt] += w[wk][kx] * row(y0+tt+wk)[kx..kx+3]
#define FMAROW(buf, wk, tt) {                                              \
        const float* wrow = wc + (wk) * 16;                                \
        _Pragma("unroll")                                                  \
        for (int kx = 0; kx < 13; ++kx) {                                  \
            float w = wrow[kx];                                            \
            _Pragma("unroll")                                              \
            for (int j = 0; j < 4; ++j)                                    \
                acc[tt][j] = fmaf(w, (buf)[kx + j], acc[tt][j]);           \
        }                                                                  \
    }

    // One ky step: window holds padded rows k..k+6 in (B0_..B6_);
    // load row k+6 into B6_, fence, then 7 output-row FMA bursts.
#define STEP(k, B0_, B1_, B2_, B3_, B4_, B5_, B6_) {                       \
        LOADROW(B6_, (k) + 6)                                              \
        __builtin_amdgcn_sched_barrier(0);                                 \
        FMAROW(B0_, k, 0) FMAROW(B1_, k, 1) FMAROW(B2_, k, 2)              \
        FMAROW(B3_, k, 3) FMAROW(B4_, k, 4) FMAROW(B5_, k, 5)              \
        FMAROW(B6_, k, 6)                                                  \
    }

    float Ra[16], Rb[16], Rc[16], Rd[16], Re[16], Rf[16], Rg[16];
    LOADROW(Ra, 0) LOADROW(Rb, 1) LOADROW(Rc, 2)
    LOADROW(Rd, 3) LOADROW(Re, 4) LOADROW(Rf, 5)

    STEP(0,  Ra, Rb, Rc, Rd, Re, Rf, Rg)
    STEP(1,  Rb, Rc, Rd, Re, Rf, Rg, Ra)
    STEP(2,  Rc, Rd, Re, Rf, Rg, Ra, Rb)
    STEP(3,  Rd, Re, Rf, Rg, Ra, Rb, Rc)
    STEP(4,  Re, Rf, Rg, Ra, Rb, Rc, Rd)
    STEP(5,  Rf, Rg, Ra, Rb, Rc, Rd, Re)
    STEP(6,  Rg, Ra, Rb, Rc, Rd, Re, Rf)
    STEP(7,  Ra, Rb, Rc, Rd, Re, Rf, Rg)
    STEP(8,  Rb, Rc, Rd, Re, Rf, Rg, Ra)
    STEP(9,  Rc, Rd, Re, Rf, Rg, Ra, Rb)
    STEP(10, Rd, Re, Rf, Rg, Ra, Rb, Rc)
    STEP(11, Re, Rf, Rg, Ra, Rb, Rc, Rd)
    STEP(12, Rf, Rg, Ra, Rb, Rc, Rd, Re)

#undef STEP
#undef FMAROW
#undef LOADROW

    float* op = out + ((size_t)(bg * NPL_ + p) * C_ + c) * (H_ * W_);
#pragma unroll
    for (int tt = 0; tt < 7; ++tt) {
        float4 v = make_float4(acc[tt][0], acc[tt][1], acc[tt][2], acc[tt][3]);
        *(float4*)(op + (y0 + tt) * W_ + x0) = v;
    }
}

extern "C" void kernel_launch(void* const* d_in, const int* in_sizes, int n_in,
                              void* d_out, int out_size, void* d_ws, size_t ws_size,
                              hipStream_t stream) {
    const float* x    = (const float*)d_in[0];
    const float* lk   = (const float*)d_in[1];
    const float* obn  = (const float*)d_in[2];
    const float* w5   = (const float*)d_in[3];
    const float* w7a  = (const float*)d_in[4];
    const float* w7b  = (const float*)d_in[5];
    const float* w3a  = (const float*)d_in[6];
    const float* w3b  = (const float*)d_in[7];
    const float* w3c  = (const float*)d_in[8];
    const float* brbn = (const float*)d_in[9];
    float* out  = (float*)d_out;

    float* weff = (float*)d_ws;            // 384*208 floats = 319488 B
    float* bias = weff + C_ * 208;         // 384 floats

    hipLaunchKernelGGL(build_weights_kernel, dim3(C_), dim3(256), 0, stream,
                       lk, obn, w5, w7a, w7b, w3a, w3b, w3c, brbn, weff, bias);

    hipLaunchKernelGGL(dwconv13_kernel, dim3((B_ / NPL_) * C_), dim3(TPB_), 0, stream,
                       x, weff, bias, out);
}

// Round 6
// 124.393 us; speedup vs baseline: 2.8977x; 2.8977x over previous
//
#include <hip/hip_runtime.h>
#include <hip/hip_bf16.h>

#define C_ 384
#define B_ 16
#define H_ 56
#define W_ 56
#define PAD_ 6
#define LW_ 68              // 56 + 2*6
#define PLANE_ (LW_ * LW_)  // 4624 floats
#define NPL_ 4              // planes (same channel, different batch) per block
#define TPB_ 448            // 7 waves; 112 threads per plane (14 xg * 8 yg)

// Fold all 7 branches (conv + BN) into one 13x13 kernel per channel + bias.
// weff layout: [C][13][16] (rows padded to 16 floats, zero-filled px>=13)
__global__ void build_weights_kernel(
    const float* __restrict__ lk, const float* __restrict__ obn,
    const float* __restrict__ w5, const float* __restrict__ w7a,
    const float* __restrict__ w7b, const float* __restrict__ w3a,
    const float* __restrict__ w3b, const float* __restrict__ w3c,
    const float* __restrict__ brbn,
    float* __restrict__ weff, float* __restrict__ bias)
{
    int c = blockIdx.x;
    int t = threadIdx.x;

    float sc[7], sh[7];
    {
        float g = obn[c], b = obn[C_ + c], m = obn[2 * C_ + c], v = obn[3 * C_ + c];
        float s = g * rsqrtf(v + 1e-5f);
        sc[0] = s; sh[0] = b - m * s;
    }
#pragma unroll
    for (int i = 0; i < 6; ++i) {
        float g = brbn[(i * 4 + 0) * C_ + c], b = brbn[(i * 4 + 1) * C_ + c];
        float m = brbn[(i * 4 + 2) * C_ + c], v = brbn[(i * 4 + 3) * C_ + c];
        float s = g * rsqrtf(v + 1e-5f);
        sc[i + 1] = s; sh[i + 1] = b - m * s;
    }

    if (t < 13 * 16) {
        int py = t >> 4, px = t & 15;
        float a = 0.f;
        if (px < 13) {
            int dy = py - 6, dx = px - 6;
            a = sc[0] * lk[c * 169 + py * 13 + px];   // 13x13, dil 1
#define ADDBR(Wp, K, R, SI)                                               \
            {                                                             \
                const int half = ((K) - 1) / 2;                           \
                if (dy % (R) == 0 && dx % (R) == 0) {                     \
                    int iy = dy / (R), ix = dx / (R);                     \
                    if (iy >= -half && iy <= half && ix >= -half && ix <= half) \
                        a += sc[SI] * Wp[c * (K) * (K) + (iy + half) * (K) + (ix + half)]; \
                }                                                         \
            }
            ADDBR(w5,  5, 1, 1)
            ADDBR(w7a, 7, 1, 2)
            ADDBR(w7b, 7, 2, 3)
            ADDBR(w3a, 3, 3, 4)
            ADDBR(w3b, 3, 4, 5)
            ADDBR(w3c, 3, 5, 6)
#undef ADDBR
        }
        weff[c * 208 + t] = a;
    }
    if (t == 0) {
        float s = 0.f;
#pragma unroll
        for (int i = 0; i < 7; ++i) s += sh[i];
        bias[c] = s;
    }
}

// Weights come from GLOBAL (vmcnt path, L1-broadcast): keeps lgkmcnt
// exclusively for the data ds_reads so counted in-order waits work and the
// row prefetch pipeline never gets drained by SMEM's out-of-order lgkm ops.
__device__ __forceinline__ void wload(float* w, const float* wc, int ky) {
    const float4* q = (const float4*)(wc + ky * 16);
    *(float4*)(w + 0) = q[0];
    *(float4*)(w + 4) = q[1];
    *(float4*)(w + 8) = q[2];
    w[12] = wc[ky * 16 + 12];
}

// tt-steps of one input row: prefetch weights for tt+1 (vmcnt) during the
// 52-FMA burst of tt. All indices compile-time; wva/wvb alternate by
// recursion so everything SROAs into registers.
template<int RR, int TT, int LAST>
__device__ __forceinline__ void ttsteps(const float* __restrict__ wc,
                                        float* wcur, float* wnxt,
                                        const float* buf, float (&acc)[7][4]) {
    if constexpr (TT < LAST) wload(wnxt, wc, RR - (TT + 1));
    __builtin_amdgcn_sched_barrier(0);
#pragma unroll
    for (int kx = 0; kx < 13; ++kx) {
        float w = wcur[kx];
#pragma unroll
        for (int j = 0; j < 4; ++j)
            acc[TT][j] = fmaf(w, buf[kx + j], acc[TT][j]);
    }
    if constexpr (TT < LAST)
        ttsteps<RR, TT + 1, LAST>(wc, wnxt, wcur, buf, acc);
}

template<int RR>
__device__ __forceinline__ void dorow(const float* __restrict__ wc,
                                      const float* buf, float (&acc)[7][4]) {
    constexpr int FIRST = (RR > 12) ? RR - 12 : 0;
    constexpr int LAST  = (RR < 6) ? RR : 6;
    float wva[16], wvb[16];
    wload(wva, wc, RR - FIRST);
    ttsteps<RR, FIRST, LAST>(wc, wva, wvb, buf, acc);
}

// One block: 4 planes (batches bg*4..bg*4+3) of channel c.
// Per plane: 112 threads, each computes a 4-wide x 7-tall output tile.
__global__ __launch_bounds__(TPB_) void dwconv13_kernel(
    const float* __restrict__ x, const float* __restrict__ weff,
    const float* __restrict__ bias, float* __restrict__ out)
{
    __shared__ float sx[NPL_ * PLANE_];   // 73984 B -> 2 blocks/CU

    int bid = blockIdx.x;
    int c  = bid % C_;
    int bg = bid / C_;   // 0..3
    int t  = threadIdx.x;

    // ---- Issue global loads FIRST so their latency hides under zeroing. ----
    // 4 planes * 56 rows * 14 float4-groups = 3136 slots = 7 per thread exactly.
    float4 vv[7];
    int    dd[7];
#pragma unroll
    for (int k = 0; k < 7; ++k) {
        int slot = t + k * TPB_;
        int p    = slot / 784;            // 784 = 56*14
        int rem  = slot - p * 784;
        int iy   = rem / 14;
        int g    = rem - iy * 14;
        const float* xp = x + ((size_t)(bg * NPL_ + p) * C_ + c) * (H_ * W_);
        vv[k] = *(const float4*)(xp + iy * W_ + g * 4);
        dd[k] = p * PLANE_ + (iy + PAD_) * LW_ + PAD_ + g * 4;
    }

    // ---- Zero the whole LDS region (halo = conv padding) meanwhile. ----
    {
        float4 z = make_float4(0.f, 0.f, 0.f, 0.f);
        float4* s4 = (float4*)sx;
#pragma unroll
        for (int k = 0; k < 11; ++k) {
            int slot = t + k * TPB_;
            if (k < 10 || slot < (NPL_ * PLANE_) / 4) s4[slot] = z;
        }
    }
    __syncthreads();

    // ---- Commit staged rows (vmcnt waits here, mostly drained). ----
#pragma unroll
    for (int k = 0; k < 7; ++k) {
        float2* wp = (float2*)(sx + dd[k]);
        wp[0] = make_float2(vv[k].x, vv[k].y);
        wp[1] = make_float2(vv[k].z, vv[k].w);
    }
    __syncthreads();

    const float* wc = weff + c * 208;
    float bv = bias[c];

    int p   = t / 112;
    int rem = t - p * 112;
    int xg  = rem % 14;       // x0 = 4*xg (16B aligned in LDS and out)
    int yg  = rem / 14;       // y0 = 7*yg
    int x0 = xg * 4, y0 = yg * 7;
    const float* sp = sx + p * PLANE_;

    float acc[7][4];
#pragma unroll
    for (int i = 0; i < 7; ++i)
#pragma unroll
        for (int j = 0; j < 4; ++j) acc[i][j] = bv;

#define LOADROW(buf, r) {                                                  \
        const float4* rp = (const float4*)(sp + (y0 + (r)) * LW_ + x0);    \
        *(float4*)((buf) + 0)  = rp[0];                                    \
        *(float4*)((buf) + 4)  = rp[1];                                    \
        *(float4*)((buf) + 8)  = rp[2];                                    \
        *(float4*)((buf) + 12) = rp[3];                                    \
    }
#define SBAR __builtin_amdgcn_sched_barrier(0);

    // 2-deep data pipeline: row r's ds_reads issued one full dorow (~700cyc)
    // before consumption; lgkmcnt(4) counted waits (DS-only, in-order).
    float Ab[16], Bb[16];
    LOADROW(Ab, 0) SBAR
    LOADROW(Bb, 1) SBAR

    dorow<0>(wc, Ab, acc);  LOADROW(Ab, 2)  SBAR
    dorow<1>(wc, Bb, acc);  LOADROW(Bb, 3)  SBAR
    dorow<2>(wc, Ab, acc);  LOADROW(Ab, 4)  SBAR
    dorow<3>(wc, Bb, acc);  LOADROW(Bb, 5)  SBAR
    dorow<4>(wc, Ab, acc);  LOADROW(Ab, 6)  SBAR
    dorow<5>(wc, Bb, acc);  LOADROW(Bb, 7)  SBAR
    dorow<6>(wc, Ab, acc);  LOADROW(Ab, 8)  SBAR
    dorow<7>(wc, Bb, acc);  LOADROW(Bb, 9)  SBAR
    dorow<8>(wc, Ab, acc);  LOADROW(Ab, 10) SBAR
    dorow<9>(wc, Bb, acc);  LOADROW(Bb, 11) SBAR
    dorow<10>(wc, Ab, acc); LOADROW(Ab, 12) SBAR
    dorow<11>(wc, Bb, acc); LOADROW(Bb, 13) SBAR
    dorow<12>(wc, Ab, acc); LOADROW(Ab, 14) SBAR
    dorow<13>(wc, Bb, acc); LOADROW(Bb, 15) SBAR
    dorow<14>(wc, Ab, acc); LOADROW(Ab, 16) SBAR
    dorow<15>(wc, Bb, acc); LOADROW(Bb, 17) SBAR
    dorow<16>(wc, Ab, acc); LOADROW(Ab, 18) SBAR
    dorow<17>(wc, Bb, acc);
    dorow<18>(wc, Ab, acc);

#undef SBAR
#undef LOADROW

    float* op = out + ((size_t)(bg * NPL_ + p) * C_ + c) * (H_ * W_);
#pragma unroll
    for (int tt = 0; tt < 7; ++tt) {
        float4 v = make_float4(acc[tt][0], acc[tt][1], acc[tt][2], acc[tt][3]);
        *(float4*)(op + (y0 + tt) * W_ + x0) = v;
    }
}

extern "C" void kernel_launch(void* const* d_in, const int* in_sizes, int n_in,
                              void* d_out, int out_size, void* d_ws, size_t ws_size,
                              hipStream_t stream) {
    const float* x    = (const float*)d_in[0];
    const float* lk   = (const float*)d_in[1];
    const float* obn  = (const float*)d_in[2];
    const float* w5   = (const float*)d_in[3];
    const float* w7a  = (const float*)d_in[4];
    const float* w7b  = (const float*)d_in[5];
    const float* w3a  = (const float*)d_in[6];
    const float* w3b  = (const float*)d_in[7];
    const float* w3c  = (const float*)d_in[8];
    const float* brbn = (const float*)d_in[9];
    float* out  = (float*)d_out;

    float* weff = (float*)d_ws;            // 384*208 floats = 319488 B
    float* bias = weff + C_ * 208;         // 384 floats

    hipLaunchKernelGGL(build_weights_kernel, dim3(C_), dim3(256), 0, stream,
                       lk, obn, w5, w7a, w7b, w3a, w3b, w3c, brbn, weff, bias);

    hipLaunchKernelGGL(dwconv13_kernel, dim3((B_ / NPL_) * C_), dim3(TPB_), 0, stream,
                       x, weff, bias, out);
}

// Round 7
// 94.690 us; speedup vs baseline: 3.8066x; 1.3137x over previous
//
#include <hip/hip_runtime.h>
#include <hip/hip_bf16.h>

#define C_ 384
#define B_ 16
#define H_ 56
#define W_ 56
#define PAD_ 6
#define LW_ 68              // 56 + 2*6
#define PLANE_ (LW_ * LW_)  // 4624 floats
#define NPL_ 4              // planes (same channel, different batch) per block
#define TPB_ 448            // 7 waves; 112 threads per plane

// Fold all 7 branches (conv + BN) into one 13x13 kernel per channel + bias.
// weff layout: [C][13][16] (rows padded to 16 floats for aligned scalar loads)
__global__ void build_weights_kernel(
    const float* __restrict__ lk, const float* __restrict__ obn,
    const float* __restrict__ w5, const float* __restrict__ w7a,
    const float* __restrict__ w7b, const float* __restrict__ w3a,
    const float* __restrict__ w3b, const float* __restrict__ w3c,
    const float* __restrict__ brbn,
    float* __restrict__ weff, float* __restrict__ bias)
{
    int c = blockIdx.x;
    int t = threadIdx.x;

    float sc[7], sh[7];
    {
        float g = obn[c], b = obn[C_ + c], m = obn[2 * C_ + c], v = obn[3 * C_ + c];
        float s = g * rsqrtf(v + 1e-5f);
        sc[0] = s; sh[0] = b - m * s;
    }
#pragma unroll
    for (int i = 0; i < 6; ++i) {
        float g = brbn[(i * 4 + 0) * C_ + c], b = brbn[(i * 4 + 1) * C_ + c];
        float m = brbn[(i * 4 + 2) * C_ + c], v = brbn[(i * 4 + 3) * C_ + c];
        float s = g * rsqrtf(v + 1e-5f);
        sc[i + 1] = s; sh[i + 1] = b - m * s;
    }

    if (t < 13 * 16) {
        int py = t >> 4, px = t & 15;
        float a = 0.f;
        if (px < 13) {
            int dy = py - 6, dx = px - 6;
            a = sc[0] * lk[c * 169 + py * 13 + px];   // 13x13, dil 1
#define ADDBR(Wp, K, R, SI)                                               \
            {                                                             \
                const int half = ((K) - 1) / 2;                           \
                if (dy % (R) == 0 && dx % (R) == 0) {                     \
                    int iy = dy / (R), ix = dx / (R);                     \
                    if (iy >= -half && iy <= half && ix >= -half && ix <= half) \
                        a += sc[SI] * Wp[c * (K) * (K) + (iy + half) * (K) + (ix + half)]; \
                }                                                         \
            }
            ADDBR(w5,  5, 1, 1)
            ADDBR(w7a, 7, 1, 2)
            ADDBR(w7b, 7, 2, 3)
            ADDBR(w3a, 3, 3, 4)
            ADDBR(w3b, 3, 4, 5)
            ADDBR(w3c, 3, 5, 6)
#undef ADDBR
        }
        weff[c * 208 + t] = a;
    }
    if (t == 0) {
        float s = 0.f;
#pragma unroll
        for (int i = 0; i < 7; ++i) s += sh[i];
        bias[c] = s;
    }
}

// One block: 4 planes (batches bg*4..bg*4+3) of channel c.
// Per plane: 112 threads, each computes a 4-wide x 7-tall output tile.
// Lane decode is yg-MAJOR (yg = r&7, xg = r>>3): 8 consecutive lanes span
// all 8 yg values; row stride 7*68 dwords ≡ 28 banks ≡ a distinct bank-quad
// per yg → every 16-lane phase of ds_read_b128 hits each bank quad exactly
// twice (the hardware minimum; 2-way aliasing is free). The old xg-major
// order put (xg, xg+8) on the SAME quad -> the stubborn 2.2e7 conflicts.
__global__ __launch_bounds__(TPB_) void dwconv13_kernel(
    const float* __restrict__ x, const float* __restrict__ weff,
    const float* __restrict__ bias, float* __restrict__ out)
{
    __shared__ float sx[NPL_ * PLANE_];   // 73984 B -> 2 blocks/CU

    int bid = blockIdx.x;
    int c  = bid % C_;
    int bg = bid / C_;   // 0..3
    int t  = threadIdx.x;

    // ---- Issue global loads FIRST so their latency hides under zeroing. ----
    // 4 planes * 56 rows * 14 float4-groups = 3136 slots = 7 per thread exactly.
    float4 vv[7];
    int    dd[7];
#pragma unroll
    for (int k = 0; k < 7; ++k) {
        int slot = t + k * TPB_;
        int p    = slot / 784;            // 784 = 56*14
        int rem  = slot - p * 784;
        int iy   = rem / 14;
        int g    = rem - iy * 14;
        const float* xp = x + ((size_t)(bg * NPL_ + p) * C_ + c) * (H_ * W_);
        vv[k] = *(const float4*)(xp + iy * W_ + g * 4);
        dd[k] = p * PLANE_ + (iy + PAD_) * LW_ + PAD_ + g * 4;
    }

    // ---- Zero the whole LDS region (halo = conv padding) meanwhile. ----
    {
        float4 z = make_float4(0.f, 0.f, 0.f, 0.f);
        float4* s4 = (float4*)sx;
#pragma unroll
        for (int k = 0; k < 11; ++k) {
            int slot = t + k * TPB_;
            if (k < 10 || slot < (NPL_ * PLANE_) / 4) s4[slot] = z;
        }
    }
    __syncthreads();

    // ---- Commit staged rows (vmcnt waits here, mostly drained). ----
#pragma unroll
    for (int k = 0; k < 7; ++k) {
        float2* wp = (float2*)(sx + dd[k]);
        wp[0] = make_float2(vv[k].x, vv[k].y);
        wp[1] = make_float2(vv[k].z, vv[k].w);
    }
    __syncthreads();

    const float* wc = weff + c * 208;   // block-uniform -> s_load path
    float bv = bias[c];

    int p   = t / 112;
    int r   = t - p * 112;
    int yg  = r & 7;          // yg-major: consecutive lanes differ in yg
    int xg  = r >> 3;         // 0..13
    int x0 = xg * 4, y0 = yg * 7;
    const float* sp = sx + p * PLANE_;

    float acc[7][4];
#pragma unroll
    for (int i = 0; i < 7; ++i)
#pragma unroll
        for (int j = 0; j < 4; ++j) acc[i][j] = bv;

#define LOADROW(buf, rr) {                                                 \
        const float4* rp = (const float4*)(sp + (y0 + (rr)) * LW_ + x0);   \
        *(float4*)((buf) + 0)  = rp[0];                                    \
        *(float4*)((buf) + 4)  = rp[1];                                    \
        *(float4*)((buf) + 8)  = rp[2];                                    \
        *(float4*)((buf) + 12) = rp[3];                                    \
    }

#define DOROW(buf, rr) {                                                   \
        _Pragma("unroll")                                                  \
        for (int tt = 0; tt < 7; ++tt) {                                   \
            int ky = (rr) - tt;                                            \
            if (ky >= 0 && ky <= 12) {   /* compile-time after unroll */   \
                const float* wrow = wc + ky * 16;                          \
                _Pragma("unroll")                                          \
                for (int kx = 0; kx < 13; ++kx) {                          \
                    float w = wrow[kx];                                    \
                    _Pragma("unroll")                                      \
                    for (int j = 0; j < 4; ++j)                            \
                        acc[tt][j] = fmaf(w, (buf)[kx + j], acc[tt][j]);   \
                }                                                          \
            }                                                              \
        }                                                                  \
    }

    // 2-deep double-buffered sliding window over the 19 padded input rows.
    float rin0[16], rin1[16];
    LOADROW(rin0, 0)
#pragma unroll
    for (int rb = 0; rb < 10; ++rb) {
        const int ra = 2 * rb;
        if (ra + 1 < 19) LOADROW(rin1, ra + 1)
        DOROW(rin0, ra)
        if (ra + 2 < 19) LOADROW(rin0, ra + 2)
        if (ra + 1 < 19) DOROW(rin1, ra + 1)
    }
#undef DOROW
#undef LOADROW

    float* op = out + ((size_t)(bg * NPL_ + p) * C_ + c) * (H_ * W_);
#pragma unroll
    for (int tt = 0; tt < 7; ++tt) {
        float4 v = make_float4(acc[tt][0], acc[tt][1], acc[tt][2], acc[tt][3]);
        *(float4*)(op + (y0 + tt) * W_ + x0) = v;
    }
}

extern "C" void kernel_launch(void* const* d_in, const int* in_sizes, int n_in,
                              void* d_out, int out_size, void* d_ws, size_t ws_size,
                              hipStream_t stream) {
    const float* x    = (const float*)d_in[0];
    const float* lk   = (const float*)d_in[1];
    const float* obn  = (const float*)d_in[2];
    const float* w5   = (const float*)d_in[3];
    const float* w7a  = (const float*)d_in[4];
    const float* w7b  = (const float*)d_in[5];
    const float* w3a  = (const float*)d_in[6];
    const float* w3b  = (const float*)d_in[7];
    const float* w3c  = (const float*)d_in[8];
    const float* brbn = (const float*)d_in[9];
    float* out  = (float*)d_out;

    float* weff = (float*)d_ws;            // 384*208 floats = 319488 B
    float* bias = weff + C_ * 208;         // 384 floats

    hipLaunchKernelGGL(build_weights_kernel, dim3(C_), dim3(256), 0, stream,
                       lk, obn, w5, w7a, w7b, w3a, w3b, w3c, brbn, weff, bias);

    hipLaunchKernelGGL(dwconv13_kernel, dim3((B_ / NPL_) * C_), dim3(TPB_), 0, stream,
                       x, weff, bias, out);
}